// Round 12
// baseline (290.727 us; speedup 1.0000x reference)
//
#include <hip/hip_runtime.h>
#include <hip/hip_bf16.h>
#include <hip/hip_fp16.h>
#include <math.h>

#define DEV_INLINE __device__ __forceinline__

typedef __attribute__((ext_vector_type(8))) short short8;
typedef __attribute__((ext_vector_type(4))) float f32x4;

constexpr int H = 128, W = 128, C = 128, B = 4;
constexpr int KK = 9;
constexpr int KT2 = 1184;         // 37 chunks * 32
constexpr int GP = 80;            // gBuf row pitch (bytes): bank-spread
constexpr int G1 = 16 * GP;       // one gBuf slot = 1280 B (16 rows)

DEV_INLINE unsigned short f2bf(float f) {
  union { float f; unsigned u; } v; v.f = f;
  unsigned r = v.u + 0x7FFFu + ((v.u >> 16) & 1u);   // RNE
  return (unsigned short)(r >> 16);
}
DEV_INLINE float ubits(unsigned u) {
  union { unsigned u; float f; } v; v.u = u; return v.f;
}
DEV_INLINE unsigned pack2bf(float a, float b) {
  float2 t; t.x = a; t.y = b;
  __hip_bfloat162 h = __float22bfloat162_rn(t);
  union { __hip_bfloat162 h; unsigned u; } c; c.h = h;
  return c.u;
}
DEV_INLINE unsigned f2h2(float a, float b) {
  __half2 h = __floats2half2_rn(a, b);
  union { __half2 h; unsigned u; } c; c.h = h;
  return c.u;
}
DEV_INLINE float2 h2f2(unsigned u) {
  union { unsigned u; __half2 h; } c; c.u = u;
  return __half22float2(c.h);
}
// full bilinear blend of one dword (2 bf16 channels) from 4 corners
DEV_INLINE unsigned blend4(unsigned TL, unsigned TR, unsigned BL, unsigned BR,
                           float w00, float w01, float w10, float w11) {
  const float lo = w00 * ubits(TL << 16) + w01 * ubits(TR << 16)
                 + w10 * ubits(BL << 16) + w11 * ubits(BR << 16);
  const float hi = w00 * ubits(TL & 0xFFFF0000u) + w01 * ubits(TR & 0xFFFF0000u)
                 + w10 * ubits(BL & 0xFFFF0000u) + w11 * ubits(BR & 0xFFFF0000u);
  return pack2bf(lo, hi);
}

// Fused deform layer (round 12). Rounds 7-11 plateau at 73-78us regardless
// of barrier count (72->36->30/interval work): the residual ~500cy/chunk of
// non-issue time is BARRIER-LOCKSTEP SKEW (16 waves/CU advance in 4-wave
// synchronized groups; every interval pays max-of-waves latency).
// Change: BLOCK = 1 WAVE = 16 POSITIONS; the wave computes ALL 8 out-tiles
// for its own positions. Producer lanes (pp=lane>>2, ps=lane&3) cover
// exactly this wave's positions; the B-fragment is one ds_read from the
// wave's OWN gBuf, shared by all 8 MFMAs. sOff/sTab/gBuf are wave-private =>
// ZERO barriers in the whole kernel (ordering = program order + compiler
// lgkmcnt). Waves drift freely; 16 independent waves/CU hide each other's
// stalls instead of sharing them. Cost: A-frags 8/chunk/wave (4x traffic,
// ~35 B/cy/CU from L1-hot 8KB tile -- cheap). LDS 6.1 KB/block; grid 4096x64;
// launch_bounds(64,4) caps VGPR at 128 (peak ~110).
template<int LAYER>
__global__ __launch_bounds__(64, 4)
void fusedL(const unsigned short* __restrict__ src,     // NHWC bf16
            const unsigned short* __restrict__ wOM,     // [37][2][64][8]
            const unsigned short* __restrict__ wS,      // [37][8][64][8]
            const float* __restrict__ bias,             // [32]
            const float* __restrict__ pA, const float* __restrict__ pB,
            const float* __restrict__ pM, const float* __restrict__ pV,
            const float* __restrict__ resid,
            unsigned short* __restrict__ outh,          // LAYER1 NHWC bf16
            float* __restrict__ outf)                   // LAYER2 NCHW fp32
{
  constexpr bool BN = (LAYER == 1);
  __shared__ __attribute__((aligned(16))) char smem[6144];
  char* gBuf = smem;                                     // [2][16][GP] = 2560
  unsigned* sTabU = (unsigned*)(smem + 2560);            // [9][16][3] = 1728
  float* sOff = (float*)(smem + 4288);                   // [16][29] = 1856

  const int lane = threadIdx.x;               // 64
  const int m16  = lane & 15;
  const int q    = lane >> 4;
  const int pp   = lane >> 2;                 // producer pos idx [0,16)
  const int ps   = lane & 3;                  // producer 16B slice

  const int raw  = blockIdx.x;                // 4096 blocks
  const int xcd  = raw & 7;
  const int slot = raw >> 3;                  // [0,512)
  const int b    = xcd >> 1;
  const int hy   = ((xcd & 1) << 6) | (slot >> 3);
  const int hx0  = (slot & 7) << 4;           // 16-wide segment
  const unsigned short* __restrict__ srcB = src + ((size_t)b << 14) * C;

  // ========== Phase 1: offset/mask conv (wave-local, no barriers) ==========
  f32x4 acc2[2];
  acc2[0] = (f32x4){0.f, 0.f, 0.f, 0.f};
  acc2[1] = (f32x4){0.f, 0.f, 0.f, 0.f};

  {  // chunk 0 (tap0, cg0) -> slot 0
    const int iy = hy - 1, ix = hx0 + pp - 1;
    uint4 v; v.x = 0; v.y = 0; v.z = 0; v.w = 0;
    if (((unsigned)iy < (unsigned)H) && ((unsigned)ix < (unsigned)W))
      v = *(const uint4*)(srcB + (size_t)(iy * W + ix) * C + (ps << 3));
    *(uint4*)(gBuf + pp * GP + (ps << 4)) = v;
  }
  uint4 pendV; pendV.x = 0; pendV.y = 0; pendV.z = 0; pendV.w = 0;
  {  // pend = chunk 1 source (tap0, cg1)
    const int iy = hy - 1, ix = hx0 + pp - 1;
    if (((unsigned)iy < (unsigned)H) && ((unsigned)ix < (unsigned)W))
      pendV = *(const uint4*)(srcB + (size_t)(iy * W + ix) * C + 32 + (ps << 3));
  }
  short8 pa0 = *(const short8*)(wOM + (size_t)lane * 8);
  short8 pa1 = *(const short8*)(wOM + (size_t)lane * 8 + 512);

  #pragma unroll 2
  for (int ch = 0; ch < 36; ++ch) {
    const int p = ch & 1;
    const short8 a0 = pa0, a1 = pa1;
    if (ch + 1 < 36) {                         // weight prefetch (L1-hot)
      const unsigned short* ap = wOM + ((size_t)((ch + 1) * 128 + lane)) * 8;
      pa0 = *(const short8*)(ap);
      pa1 = *(const short8*)(ap + 512);
    }
    uint4 newV; newV.x = 0; newV.y = 0; newV.z = 0; newV.w = 0;
    if (ch + 2 < 36) {                         // source for ch+2
      const int t2 = (ch + 2) >> 2, c2 = (ch + 2) & 3;
      const int ky = t2 / 3, kx = t2 - 3 * (t2 / 3);
      const int iy = hy + ky - 1;
      const int ix = hx0 + pp + kx - 1;
      if (((unsigned)iy < (unsigned)H) && ((unsigned)ix < (unsigned)W))
        newV = *(const uint4*)(srcB + (size_t)(iy * W + ix) * C + (c2 << 5) + (ps << 3));
    }
    if (ch + 1 < 36)                           // write pend (chunk ch+1)
      *(uint4*)(gBuf + (p ^ 1) * G1 + pp * GP + (ps << 4)) = pendV;
    const short8 bf = *(const short8*)(gBuf + p * G1 + m16 * GP + (q << 4));
    acc2[0] = __builtin_amdgcn_mfma_f32_16x16x32_bf16(a0, bf, acc2[0], 0, 0, 0);
    acc2[1] = __builtin_amdgcn_mfma_f32_16x16x32_bf16(a1, bf, acc2[1], 0, 0, 0);
    pendV = newV;
  }
  if constexpr (BN) {   // validity column chunk (register B)
    union { unsigned u[4]; short8 s; } bfr;
    float sv[8];
    #pragma unroll
    for (int j = 0; j < 8; ++j) {
      const int kj = (q << 3) + j;
      float s = 0.f;
      if (kj < KK) {
        const int ky = kj / 3, kx = kj - 3 * (kj / 3);
        const int iy = hy + ky - 1, ix = hx0 + m16 + kx - 1;
        s = (((unsigned)iy < (unsigned)H) && ((unsigned)ix < (unsigned)W)) ? 1.f : 0.f;
      }
      sv[j] = s;
    }
    #pragma unroll
    for (int t = 0; t < 4; ++t) bfr.u[t] = pack2bf(sv[2 * t], sv[2 * t + 1]);
    const unsigned short* ap = wOM + ((size_t)36 * 128 + lane) * 8;
    acc2[0] = __builtin_amdgcn_mfma_f32_16x16x32_bf16(*(const short8*)(ap), bfr.s, acc2[0], 0, 0, 0);
    acc2[1] = __builtin_amdgcn_mfma_f32_16x16x32_bf16(*(const short8*)(ap + 512), bfr.s, acc2[1], 0, 0, 0);
  }
  // epilogue -> sOff (col = m16 -> pos, row = ot*16 + q*4+rg -> o); wave-local
  #pragma unroll
  for (int ot = 0; ot < 2; ++ot) {
    #pragma unroll
    for (int rg = 0; rg < 4; ++rg) {
      const int o = ot * 16 + (q << 2) + rg;
      if (o < 27) {
        float v = acc2[ot][rg] + bias[o];
        if (o >= 18) v = 2.f / (1.f + expf(-v));
        sOff[m16 * 29 + o] = v;
      }
    }
  }

  // ========== Phase 2: bilinear table -> sTab (wave-local) =================
  // entry: {rowpair id, pk(w00,w01), pk(w10,w11)}, w = mv*wy*wx premultiplied
  {
    const float* myOff = sOff + m16 * 29;      // all q redundant; q==0 writes
    #pragma unroll
    for (int tap = 0; tap < 9; ++tap) {
      const int ky = tap / 3, kx = tap - 3 * (tap / 3);
      const float oy = myOff[2 * tap];
      const float ox = myOff[2 * tap + 1];
      const float mv = myOff[18 + tap];
      const float py = (float)(hy - 1 + ky) + oy;
      const float px = (float)(hx0 + m16 - 1 + kx) + ox;
      const float fy = floorf(py), fx = floorf(px);
      const float ay = py - fy, ax = px - fx;
      const int y0 = (int)fy, x0 = (int)fx;
      const int y1 = y0 + 1, x1 = x0 + 1;
      const float wyt = (1.f - ay) * (((unsigned)y0 < (unsigned)H) ? 1.f : 0.f);
      const float wyb = ay * (((unsigned)y1 < (unsigned)H) ? 1.f : 0.f);
      const int y0c = min(max(y0, 0), H - 1), y1c = min(max(y1, 0), H - 1);
      const int bx  = min(max(x0, 0), W - 2);
      float wA = 0.f, wB = 0.f;
      if (x0 == bx)          { wA = 1.f - ax; wB = ax; }
      else if (x1 == bx)     { wA = ax; }
      else if (x0 == bx + 1) { wB = 1.f - ax; }
      if (q == 0) {
        const int tb = (tap * 16 + m16) * 3;
        sTabU[tb + 0] = (unsigned)(y0c * W + bx) | ((unsigned)(y1c * W + bx) << 16);
        sTabU[tb + 1] = f2h2(mv * wyt * wA, mv * wyt * wB);
        sTabU[tb + 2] = f2h2(mv * wyb * wA, mv * wyb * wB);
      }
    }
  }

  // ========== Phase 3: deform GEMM (wave-local, no barriers) ===============
  f32x4 acc[8];
  #pragma unroll
  for (int i = 0; i < 8; ++i) acc[i] = (f32x4){0.f, 0.f, 0.f, 0.f};

  unsigned wB0, wB1;                 // blend weights for pending chunk's tap
  unsigned idI, iw0, iw1;            // issue tab (tap of chunk being issued)
  {
    const int tb = pp * 3;
    idI = sTabU[tb]; iw0 = sTabU[tb + 1]; iw1 = sTabU[tb + 2];
    wB0 = iw0; wB1 = iw1;
  }
  {  // chunk 0: load + blend + write slot 0
    const int cbn = (ps << 3);
    const unsigned short* pT  = srcB + (size_t)(idI & 0xFFFFu) * C + cbn;
    const unsigned short* pBm = srcB + (size_t)(idI >> 16) * C + cbn;
    const uint4 TL = *(const uint4*)(pT),  TR = *(const uint4*)(pT + C);
    const uint4 BL = *(const uint4*)(pBm), BR = *(const uint4*)(pBm + C);
    const float2 wa = h2f2(iw0), wb = h2f2(iw1);
    uint4 o;
    o.x = blend4(TL.x, TR.x, BL.x, BR.x, wa.x, wa.y, wb.x, wb.y);
    o.y = blend4(TL.y, TR.y, BL.y, BR.y, wa.x, wa.y, wb.x, wb.y);
    o.z = blend4(TL.z, TR.z, BL.z, BR.z, wa.x, wa.y, wb.x, wb.y);
    o.w = blend4(TL.w, TR.w, BL.w, BR.w, wa.x, wa.y, wb.x, wb.y);
    *(uint4*)(gBuf + pp * GP + (ps << 4)) = o;
  }
  uint4 pTL, pTR, pBL, pBR;
  {  // pend = corners for chunk 1 (tap0, cg1)
    const int cbn = 32 + (ps << 3);
    const unsigned short* pT  = srcB + (size_t)(idI & 0xFFFFu) * C + cbn;
    const unsigned short* pBm = srcB + (size_t)(idI >> 16) * C + cbn;
    pTL = *(const uint4*)(pT);  pTR = *(const uint4*)(pT + C);
    pBL = *(const uint4*)(pBm); pBR = *(const uint4*)(pBm + C);
  }

  #pragma unroll 2
  for (int ch = 0; ch < 36; ++ch) {
    const int p = ch & 1;
    // refresh issue tab at tap boundary of the chunk being issued (ch+2)
    if ((((ch + 2) & 3) == 0) && (ch + 2 < 36)) {
      const int tb = (((ch + 2) >> 2) * 16 + pp) * 3;
      idI = sTabU[tb]; iw0 = sTabU[tb + 1]; iw1 = sTabU[tb + 2];
    }
    // A-fragments batch 1 (global, L1-hot; shared tile across waves)
    const unsigned short* apb = wS + (size_t)ch * 4096 + (size_t)lane * 8;
    const short8 af0 = *(const short8*)(apb);
    const short8 af1 = *(const short8*)(apb + 512);
    const short8 af2 = *(const short8*)(apb + 1024);
    const short8 af3 = *(const short8*)(apb + 1536);
    // blend pending chunk (ch+1) -> write other slot
    if (ch + 1 < 36) {
      const float2 wa = h2f2(wB0), wb = h2f2(wB1);
      uint4 o;
      o.x = blend4(pTL.x, pTR.x, pBL.x, pBR.x, wa.x, wa.y, wb.x, wb.y);
      o.y = blend4(pTL.y, pTR.y, pBL.y, pBR.y, wa.x, wa.y, wb.x, wb.y);
      o.z = blend4(pTL.z, pTR.z, pBL.z, pBR.z, wa.x, wa.y, wb.x, wb.y);
      o.w = blend4(pTL.w, pTR.w, pBL.w, pBR.w, wa.x, wa.y, wb.x, wb.y);
      *(uint4*)(gBuf + (p ^ 1) * G1 + pp * GP + (ps << 4)) = o;
    }
    // issue corners for chunk ch+2
    if (ch + 2 < 36) {
      const int cbn = (((ch + 2) & 3) << 5) + (ps << 3);
      const unsigned short* pT  = srcB + (size_t)(idI & 0xFFFFu) * C + cbn;
      const unsigned short* pBm = srcB + (size_t)(idI >> 16) * C + cbn;
      pTL = *(const uint4*)(pT);  pTR = *(const uint4*)(pT + C);
      pBL = *(const uint4*)(pBm); pBR = *(const uint4*)(pBm + C);
    }
    // consumer: one B-frag (own gBuf) shared by all 8 MFMAs
    const short8 bf = *(const short8*)(gBuf + p * G1 + m16 * GP + (q << 4));
    acc[0] = __builtin_amdgcn_mfma_f32_16x16x32_bf16(af0, bf, acc[0], 0, 0, 0);
    acc[1] = __builtin_amdgcn_mfma_f32_16x16x32_bf16(af1, bf, acc[1], 0, 0, 0);
    acc[2] = __builtin_amdgcn_mfma_f32_16x16x32_bf16(af2, bf, acc[2], 0, 0, 0);
    acc[3] = __builtin_amdgcn_mfma_f32_16x16x32_bf16(af3, bf, acc[3], 0, 0, 0);
    const short8 af4 = *(const short8*)(apb + 2048);
    const short8 af5 = *(const short8*)(apb + 2560);
    const short8 af6 = *(const short8*)(apb + 3072);
    const short8 af7 = *(const short8*)(apb + 3584);
    acc[4] = __builtin_amdgcn_mfma_f32_16x16x32_bf16(af4, bf, acc[4], 0, 0, 0);
    acc[5] = __builtin_amdgcn_mfma_f32_16x16x32_bf16(af5, bf, acc[5], 0, 0, 0);
    acc[6] = __builtin_amdgcn_mfma_f32_16x16x32_bf16(af6, bf, acc[6], 0, 0, 0);
    acc[7] = __builtin_amdgcn_mfma_f32_16x16x32_bf16(af7, bf, acc[7], 0, 0, 0);
    // rotate blend weights when the NEXT blend target crosses a tap boundary
    if (((ch + 2) & 3) == 0) { wB0 = iw0; wB1 = iw1; }
  }

  if constexpr (BN) {   // chunk 36: BN-shift column; B = per-tap sums (sTab)
    union { unsigned u[4]; short8 s; } bfr;
    float sv[8];
    #pragma unroll
    for (int j = 0; j < 8; ++j) {
      const int k = (q << 3) + j;
      float s = 0.f;
      if (k < KK) {
        const int tb = (k * 16 + m16) * 3;
        const float2 a = h2f2(sTabU[tb + 1]);
        const float2 c = h2f2(sTabU[tb + 2]);
        s = a.x + a.y + c.x + c.y;
      }
      sv[j] = s;
    }
    #pragma unroll
    for (int t = 0; t < 4; ++t) bfr.u[t] = pack2bf(sv[2 * t], sv[2 * t + 1]);
    const unsigned short* apb = wS + (size_t)36 * 4096 + (size_t)lane * 8;
    #pragma unroll
    for (int ot = 0; ot < 8; ++ot) {
      const short8 af = *(const short8*)(apb + ot * 512);
      acc[ot] = __builtin_amdgcn_mfma_f32_16x16x32_bf16(af, bfr.s, acc[ot], 0, 0, 0);
    }
  }

  // ---- epilogue ----
  #pragma unroll
  for (int ot = 0; ot < 8; ++ot) {
    if constexpr (LAYER == 1) {
      const float a0 = pA[ot * 16 + (q << 2) + 0];
      const float a1 = pA[ot * 16 + (q << 2) + 1];
      const float a2 = pA[ot * 16 + (q << 2) + 2];
      const float a3 = pA[ot * 16 + (q << 2) + 3];
      const float v0 = acc[ot][0], v1 = acc[ot][1];
      const float v2 = acc[ot][2], v3 = acc[ot][3];
      uint2 st;
      st.x = pack2bf(v0 > 0.f ? v0 : a0 * v0, v1 > 0.f ? v1 : a1 * v1);
      st.y = pack2bf(v2 > 0.f ? v2 : a2 * v2, v3 > 0.f ? v3 : a3 * v3);
      const int n = (b << 14) + hy * W + hx0 + m16;
      *(uint2*)(outh + (size_t)n * C + ot * 16 + (q << 2)) = st;
    } else {
      #pragma unroll
      for (int rg = 0; rg < 4; ++rg) {
        const int o = ot * 16 + (q << 2) + rg;
        const float s  = pA[o] * rsqrtf(pV[o] + 1e-5f);
        const float sh = pB[o] - pM[o] * s;
        const size_t oi = (((size_t)(b * C + o)) << 14) + hy * W + hx0 + m16;
        outf[oi] = acc[ot][rg] * s + sh + resid[oi];
      }
    }
  }
}

// NCHW fp32 -> NHWC bf16, LDS-tiled (coalesced loads AND stores)
__global__ __launch_bounds__(256, 4)
void xcvt3(const float* __restrict__ x, unsigned short* __restrict__ xb)
{
  __shared__ unsigned tile[64 * 69];
  const int b   = blockIdx.y;
  const int p0  = blockIdx.x * 64;
  const int tid = threadIdx.x;
  const int pl  = tid & 63;
  const int cg  = tid >> 6;
  const float* __restrict__ xp = x + (((size_t)(b * C) + cg * 32) << 14) + p0 + pl;
  #pragma unroll
  for (int j = 0; j < 16; ++j) {
    const float a = xp[(size_t)(2 * j) << 14];
    const float c = xp[(size_t)(2 * j + 1) << 14];
    tile[pl * 69 + cg * 16 + j] = pack2bf(a, c);
  }
  __syncthreads();
  const int pl2 = tid >> 2;
  const int cq  = tid & 3;
  unsigned* dst = (unsigned*)(xb + (((size_t)(b << 14)) + p0 + pl2) * C + cq * 32);
  #pragma unroll
  for (int k = 0; k < 16; k += 4) {
    uint4 v;
    v.x = tile[pl2 * 69 + cq * 16 + k];
    v.y = tile[pl2 * 69 + cq * 16 + k + 1];
    v.z = tile[pl2 * 69 + cq * 16 + k + 2];
    v.w = tile[pl2 * 69 + cq * 16 + k + 3];
    *(uint4*)(dst + k) = v;
  }
}

// Swizzled weights, tap-major chunks: wS[((ch*NT+ot)*64+lane)*8+j] =
// w[o=ot*16+(lane&15)][c=(ch&3)*32+(lane>>4)*8+j][tap=ch>>2] (ch<36);
// ch==36: BN-shift col (kj=(lane>>4)*8+j < 9), layer-1 only.
__global__ void prep5(const float* __restrict__ w1, const float* __restrict__ w2,
                      const float* __restrict__ ow1, const float* __restrict__ mw1,
                      const float* __restrict__ ob1, const float* __restrict__ mb1,
                      const float* __restrict__ ow2, const float* __restrict__ mw2,
                      const float* __restrict__ ob2, const float* __restrict__ mb2,
                      const float* __restrict__ g, const float* __restrict__ bb,
                      const float* __restrict__ m, const float* __restrict__ v,
                      unsigned short* __restrict__ wb1, unsigned short* __restrict__ wb2,
                      unsigned short* __restrict__ wom1, unsigned short* __restrict__ wom2,
                      float* __restrict__ bias1, float* __restrict__ bias2)
{
  const int i = blockIdx.x * 256 + threadIdx.x;
  if (i < 128 * KT2) {              // deform, NT=8
    const int j = i & 7, lane = (i >> 3) & 63, ot = (i >> 9) & 7, ch = i >> 12;
    const int o = ot * 16 + (lane & 15);
    const int qj = ((lane >> 4) << 3) + j;
    unsigned short v1 = 0, v2 = 0;
    if (ch < 36) {
      const int tap = ch >> 2;
      const int c   = ((ch & 3) << 5) + qj;
      const float s = g[c] * rsqrtf(v[c] + 1e-5f);
      v1 = f2bf(w1[(size_t)(o * 128 + c) * 9 + tap] * s);
      v2 = f2bf(w2[(size_t)(o * 128 + c) * 9 + tap]);
    } else if (qj < KK) {
      float acc = 0.f;
      for (int c = 0; c < 128; ++c) {
        const float s  = g[c] * rsqrtf(v[c] + 1e-5f);
        const float sh = bb[c] - m[c] * s;
        acc += w1[(size_t)(o * 128 + c) * 9 + qj] * sh;
      }
      v1 = f2bf(acc);
    }
    wb1[i] = v1; wb2[i] = v2;
  }
  if (i < 32 * KT2) {               // offset/mask, NT=2
    const int j = i & 7, lane = (i >> 3) & 63, ot = (i >> 9) & 1, ch = i >> 10;
    const int o = ot * 16 + (lane & 15);
    const int qj = ((lane >> 4) << 3) + j;
    unsigned short v1 = 0, v2 = 0;
    if (ch < 36) {
      const int tap = ch >> 2;
      const int c   = ((ch & 3) << 5) + qj;
      const float s = g[c] * rsqrtf(v[c] + 1e-5f);
      if (o < 18) {
        v1 = f2bf(ow1[(size_t)(o * 128 + c) * 9 + tap] * s);
        v2 = f2bf(ow2[(size_t)(o * 128 + c) * 9 + tap]);
      } else if (o < 27) {
        v1 = f2bf(mw1[(size_t)((o - 18) * 128 + c) * 9 + tap] * s);
        v2 = f2bf(mw2[(size_t)((o - 18) * 128 + c) * 9 + tap]);
      }
    } else if (qj < KK && o < 27) {
      const float* wsrc = (o < 18) ? ow1 + (size_t)o * 1152
                                   : mw1 + (size_t)(o - 18) * 1152;
      float acc = 0.f;
      for (int c = 0; c < 128; ++c) {
        const float s  = g[c] * rsqrtf(v[c] + 1e-5f);
        const float sh = bb[c] - m[c] * s;
        acc += wsrc[(size_t)c * 9 + qj] * sh;
      }
      v1 = f2bf(acc);
    }
    wom1[i] = v1; wom2[i] = v2;
  }
  if (i < 32) {
    float b1 = 0.f, b2 = 0.f;
    if (i < 18)      { b1 = ob1[i];      b2 = ob2[i]; }
    else if (i < 27) { b1 = mb1[i - 18]; b2 = mb2[i - 18]; }
    bias1[i] = b1; bias2[i] = b2;
  }
}

extern "C" void kernel_launch(void* const* d_in, const int* in_sizes, int n_in,
                              void* d_out, int out_size, void* d_ws, size_t ws_size,
                              hipStream_t stream)
{
  const float* x     = (const float*)d_in[0];
  const float* bn1g  = (const float*)d_in[1];
  const float* bn1b  = (const float*)d_in[2];
  const float* bn1m  = (const float*)d_in[3];
  const float* bn1v  = (const float*)d_in[4];
  const float* ow1   = (const float*)d_in[5];
  const float* ob1   = (const float*)d_in[6];
  const float* mw1   = (const float*)d_in[7];
  const float* mb1   = (const float*)d_in[8];
  const float* w1    = (const float*)d_in[9];
  const float* alpha = (const float*)d_in[10];
  const float* ow2   = (const float*)d_in[11];
  const float* ob2   = (const float*)d_in[12];
  const float* mw2   = (const float*)d_in[13];
  const float* mb2   = (const float*)d_in[14];
  const float* w2    = (const float*)d_in[15];
  const float* bn2g  = (const float*)d_in[16];
  const float* bn2b  = (const float*)d_in[17];
  const float* bn2m  = (const float*)d_in[18];
  const float* bn2v  = (const float*)d_in[19];
  float* out = (float*)d_out;

  char* wsp = (char*)d_ws;
  unsigned short* xbf  = (unsigned short*)(wsp);             // NHWC bf16
  unsigned short* r2bf = (unsigned short*)(wsp + 16777216);  // NHWC bf16
  unsigned short* wb1  = (unsigned short*)(wsp + 40632320);  // 303104
  unsigned short* wb2  = (unsigned short*)(wsp + 40935424);  // 303104
  unsigned short* wom1 = (unsigned short*)(wsp + 41238528);  // 75776
  unsigned short* wom2 = (unsigned short*)(wsp + 41314304);  // 75776
  float* bias1 = (float*)(wsp + 41390080);
  float* bias2 = (float*)(wsp + 41390208);

  xcvt3<<<dim3(256, 4), 256, 0, stream>>>(x, xbf);
  prep5<<<(128 * KT2 + 255) / 256, 256, 0, stream>>>(
      w1, w2, ow1, mw1, ob1, mb1, ow2, mw2, ob2, mb2,
      bn1g, bn1b, bn1m, bn1v, wb1, wb2, wom1, wom2, bias1, bias2);

  fusedL<1><<<4096, 64, 0, stream>>>(xbf, wom1, wb1, bias1, alpha,
      nullptr, nullptr, nullptr, nullptr, r2bf, nullptr);
  fusedL<2><<<4096, 64, 0, stream>>>(r2bf, wom2, wb2, bias2, bn2g,
      bn2b, bn2m, bn2v, x, nullptr, out);
}